// Round 11
// baseline (105.441 us; speedup 1.0000x reference)
//
#include <hip/hip_runtime.h>

// GradientCurvatureAttention: fused depthwise-conv + curvature + channel-softmax + scale.
// x: [B=16, C=128, H=128, W=128] fp32, NCHW. out: same shape.
//
// Round 11: R7 base (best: 63.9us, 2048 x (32,8), CGRP=8, CPW=16) + VALU diet:
//  - raw v_rsq / v_rcp / v_exp via __builtin_amdgcn_* (no IEEE fixup chains)
//  - wave-uniform row-edge skip: the 8 row-mask muls/iter execute only in the
//    2 edge-row blocks (h is block-uniform -> s_cbranch, no divergence)
// R8 (2 rows/thr): occupancy collapse. R9 (manual pipeline): VGPR 184 spill.
// R10 (paired iters): neutral. Memory side is at the floor; VALU is the lever.

#define GCA_B 16
#define GCA_C 128
#define GCA_H 128
#define GCA_W 128
#define CGRP  8            // channel groups (blockDim.y)
#define CPW   (GCA_C/CGRP) // 16 channels per group

#define GCA_LOG2E 1.44269504088896f

__device__ __forceinline__ float gca_score11(float cpl, float cpc, float cpr,
                                             float cml, float cmc, float cmr,
                                             float cyl, float cyc, float cyr) {
    const float Gx  = cpl - cpr;                       // [1,2,1]v x [1,0,-1]h
    const float Gy  = fmaf(2.f, cmc, cml + cmr);       // [1,0,-1]v x [1,2,1]h
    const float Ixx = fmaf(-2.f, cpc, cpl + cpr);      // [1,2,1]v x [1,-2,1]h
    const float Ixy = cmr - cml;                       // [1,0,-1]v x [-1,0,1]h
    const float Iyy = fmaf(2.f, cyc, cyl + cyr);       // [1,-2,1]v x [1,2,1]h
    const float gy2 = Gy * Gy;
    const float g2e = fmaf(Gx, Gx, gy2 + 1e-6f);
    const float r   = __builtin_amdgcn_rsqf(g2e);      // raw v_rsq_f32
    const float gm  = g2e * r;                         // sqrt(g2e)
    const float t   = Gx * Iyy;
    const float p   = Gy * Ixy;
    const float inner = fmaf(-2.f, p, t);              // Gx*Iyy - 2*Gy*Ixy
    const float q   = gy2 * Ixx;
    const float num = fmaf(Gx, inner, q);
    const float r3  = (r * r) * r;
    return fmaf(num, r3, gm);                          // grad_mag + curvature
}

__global__ __launch_bounds__(256) void gca_fused11(const float* __restrict__ x,
                                                   float* __restrict__ out) {
    const int tx = threadIdx.x;                 // 0..31 : pixel quad, w0 = 4*tx
    const int ty = threadIdx.y;                 // 0..7  : channel group

    // XCD swizzle: 2048 blocks (= B*H, h minor), 256 consecutive ids per XCD.
    const int id  = blockIdx.x;
    const int swz = ((id & 7) << 8) | (id >> 3);
    const int h   = swz & 127;
    const int b   = swz >> 7;

    const int w0 = tx * 4;
    const int c0 = ty * CPW;

    const int hm = (h > 0) ? h - 1 : 0;
    const int hp = (h < GCA_H - 1) ? h + 1 : GCA_H - 1;
    const bool edgeh = (h == 0) || (h == GCA_H - 1);   // block-uniform
    const float mh0 = (h > 0) ? 1.f : 0.f;
    const float mh2 = (h < GCA_H - 1) ? 1.f : 0.f;
    const float mwA = (tx > 0) ? 1.f : 0.f;    // left halo exists
    const float mwB = (tx < 31) ? 1.f : 0.f;   // right halo exists

    const size_t plane = (size_t)GCA_H * GCA_W;
    const float* base = x   + ((size_t)b * GCA_C + c0) * plane;
    float* obase      = out + ((size_t)b * GCA_C + c0) * plane;

    const int r0off = hm * GCA_W + w0;
    const int r1off = h  * GCA_W + w0;
    const int r2off = hp * GCA_W + w0;

    float4 s[CPW];                       // scores, then exp values
    float4 lmax = make_float4(-3.0e38f, -3.0e38f, -3.0e38f, -3.0e38f);

    // Pass 1: conv + curvature scores for 4 pixels x 16 channels.
    #pragma unroll
    for (int i = 0; i < CPW; ++i) {
        const float* p = base + (size_t)i * plane;
        float4 v0 = *(const float4*)(p + r0off);
        const float4 v1 = *(const float4*)(p + r1off);
        float4 v2 = *(const float4*)(p + r2off);

        // Row-edge masks only in the two edge-row blocks (wave-uniform).
        if (edgeh) {
            v0.x *= mh0; v0.y *= mh0; v0.z *= mh0; v0.w *= mh0;
            v2.x *= mh2; v2.y *= mh2; v2.z *= mh2; v2.w *= mh2;
        }

        // Own column sums for cols w0..w0+3 (A..D).
        const float cpA = fmaf(2.f, v1.x, v0.x + v2.x);
        const float cmA = v0.x - v2.x;
        const float cyA = fmaf(-4.f, v1.x, cpA);
        const float cpB = fmaf(2.f, v1.y, v0.y + v2.y);
        const float cmB = v0.y - v2.y;
        const float cyB = fmaf(-4.f, v1.y, cpB);
        const float cpC = fmaf(2.f, v1.z, v0.z + v2.z);
        const float cmC = v0.z - v2.z;
        const float cyC = fmaf(-4.f, v1.z, cpC);
        const float cpD = fmaf(2.f, v1.w, v0.w + v2.w);
        const float cmD = v0.w - v2.w;
        const float cyD = fmaf(-4.f, v1.w, cpD);

        // Halo column sums from neighbor lanes (row masks already applied).
        const float cpL = __shfl_up(cpD, 1) * mwA;
        const float cmL = __shfl_up(cmD, 1) * mwA;
        const float cyL = __shfl_up(cyD, 1) * mwA;
        const float cpR = __shfl_down(cpA, 1) * mwB;
        const float cmR = __shfl_down(cmA, 1) * mwB;
        const float cyR = __shfl_down(cyA, 1) * mwB;

        float4 sc;
        sc.x = gca_score11(cpL, cpA, cpB,  cmL, cmA, cmB,  cyL, cyA, cyB);
        sc.y = gca_score11(cpA, cpB, cpC,  cmA, cmB, cmC,  cyA, cyB, cyC);
        sc.z = gca_score11(cpB, cpC, cpD,  cmB, cmC, cmD,  cyB, cyC, cyD);
        sc.w = gca_score11(cpC, cpD, cpR,  cmC, cmD, cmR,  cyC, cyD, cyR);
        s[i] = sc;
        lmax.x = fmaxf(lmax.x, sc.x);
        lmax.y = fmaxf(lmax.y, sc.y);
        lmax.z = fmaxf(lmax.z, sc.z);
        lmax.w = fmaxf(lmax.w, sc.w);
    }

    // Cross-group softmax reduction (per pixel, over the 8 channel groups).
    __shared__ float4 redmax[CGRP][32];
    __shared__ float4 redsum[CGRP][32];

    redmax[ty][tx] = lmax;
    __syncthreads();
    float4 gmax = make_float4(-3.0e38f, -3.0e38f, -3.0e38f, -3.0e38f);
    #pragma unroll
    for (int g = 0; g < CGRP; ++g) {
        const float4 m = redmax[g][tx];
        gmax.x = fmaxf(gmax.x, m.x);
        gmax.y = fmaxf(gmax.y, m.y);
        gmax.z = fmaxf(gmax.z, m.z);
        gmax.w = fmaxf(gmax.w, m.w);
    }

    float4 lsum = make_float4(0.f, 0.f, 0.f, 0.f);
    #pragma unroll
    for (int i = 0; i < CPW; ++i) {
        float4 e;
        e.x = __builtin_amdgcn_exp2f((s[i].x - gmax.x) * GCA_LOG2E);
        e.y = __builtin_amdgcn_exp2f((s[i].y - gmax.y) * GCA_LOG2E);
        e.z = __builtin_amdgcn_exp2f((s[i].z - gmax.z) * GCA_LOG2E);
        e.w = __builtin_amdgcn_exp2f((s[i].w - gmax.w) * GCA_LOG2E);
        s[i] = e;
        lsum.x += e.x; lsum.y += e.y; lsum.z += e.z; lsum.w += e.w;
    }
    redsum[ty][tx] = lsum;
    __syncthreads();
    float4 tot = make_float4(0.f, 0.f, 0.f, 0.f);
    #pragma unroll
    for (int g = 0; g < CGRP; ++g) {
        const float4 sm = redsum[g][tx];
        tot.x += sm.x; tot.y += sm.y; tot.z += sm.z; tot.w += sm.w;
    }
    const float invx = __builtin_amdgcn_rcpf(tot.x);
    const float invy = __builtin_amdgcn_rcpf(tot.y);
    const float invz = __builtin_amdgcn_rcpf(tot.z);
    const float invw = __builtin_amdgcn_rcpf(tot.w);

    // Epilogue: out = (softmax + 1) * x; center row reloaded (L2-resident).
    #pragma unroll
    for (int i = 0; i < CPW; ++i) {
        const float4 xv = *(const float4*)(base + (size_t)i * plane + r1off);
        float4 o;
        o.x = fmaf(s[i].x * invx, xv.x, xv.x);
        o.y = fmaf(s[i].y * invy, xv.y, xv.y);
        o.z = fmaf(s[i].z * invz, xv.z, xv.z);
        o.w = fmaf(s[i].w * invw, xv.w, xv.w);
        *(float4*)(obase + (size_t)i * plane + r1off) = o;
    }
}

extern "C" void kernel_launch(void* const* d_in, const int* in_sizes, int n_in,
                              void* d_out, int out_size, void* d_ws, size_t ws_size,
                              hipStream_t stream) {
    (void)in_sizes; (void)n_in; (void)d_ws; (void)ws_size; (void)out_size;
    const float* x = (const float*)d_in[0];
    float* out = (float*)d_out;
    dim3 block(32, CGRP, 1);
    dim3 grid(GCA_B * GCA_H, 1, 1);   // 2048 blocks, swizzled in-kernel
    gca_fused11<<<grid, block, 0, stream>>>(x, out);
}

// Round 12
// 63.884 us; speedup vs baseline: 1.6505x; 1.6505x over previous
//
#include <hip/hip_runtime.h>

// GradientCurvatureAttention: fused depthwise-conv + curvature + channel-softmax + scale.
// x: [B=16, C=128, H=128, W=128] fp32, NCHW. out: same shape.
//
// Round 12: R7 verbatim (best clean structure: 63.9us, VGPR=64) + pure
// intrinsic substitution (v_rsq / v_exp / v_rcp, no IEEE fixup chains).
// NO in-loop branches and NO launch-bound occupancy forcing: R9/R11 showed
// any branch inside the x16-unrolled body blows VGPR 64 -> 160-184.

#define GCA_B 16
#define GCA_C 128
#define GCA_H 128
#define GCA_W 128
#define CGRP  8            // channel groups (blockDim.y)
#define CPW   (GCA_C/CGRP) // 16 channels per group

#define GCA_LOG2E 1.44269504088896f

__device__ __forceinline__ float gca_score12(float cpl, float cpc, float cpr,
                                             float cml, float cmc, float cmr,
                                             float cyl, float cyc, float cyr) {
    const float Gx  = cpl - cpr;                       // [1,2,1]v x [1,0,-1]h
    const float Gy  = fmaf(2.f, cmc, cml + cmr);       // [1,0,-1]v x [1,2,1]h
    const float Ixx = fmaf(-2.f, cpc, cpl + cpr);      // [1,2,1]v x [1,-2,1]h
    const float Ixy = cmr - cml;                       // [1,0,-1]v x [-1,0,1]h
    const float Iyy = fmaf(2.f, cyc, cyl + cyr);       // [1,-2,1]v x [1,2,1]h
    const float gy2 = Gy * Gy;
    const float g2e = fmaf(Gx, Gx, gy2 + 1e-6f);
    const float r   = __builtin_amdgcn_rsqf(g2e);      // raw v_rsq_f32
    const float gm  = g2e * r;                         // sqrt(g2e)
    const float t   = Gx * Iyy;
    const float p   = Gy * Ixy;
    const float inner = fmaf(-2.f, p, t);              // Gx*Iyy - 2*Gy*Ixy
    const float q   = gy2 * Ixx;
    const float num = fmaf(Gx, inner, q);
    const float r3  = (r * r) * r;
    return fmaf(num, r3, gm);                          // grad_mag + curvature
}

__global__ __launch_bounds__(256) void gca_fused12(const float* __restrict__ x,
                                                   float* __restrict__ out) {
    const int tx = threadIdx.x;                 // 0..31 : pixel quad, w0 = 4*tx
    const int ty = threadIdx.y;                 // 0..7  : channel group

    // XCD swizzle: 2048 blocks (= B*H, h minor), 256 consecutive ids per XCD.
    const int id  = blockIdx.x;
    const int swz = ((id & 7) << 8) | (id >> 3);
    const int h   = swz & 127;
    const int b   = swz >> 7;

    const int w0 = tx * 4;
    const int c0 = ty * CPW;

    const int hm = (h > 0) ? h - 1 : 0;
    const int hp = (h < GCA_H - 1) ? h + 1 : GCA_H - 1;
    const float mh0 = (h > 0) ? 1.f : 0.f;
    const float mh2 = (h < GCA_H - 1) ? 1.f : 0.f;
    const float mwA = (tx > 0) ? 1.f : 0.f;    // left halo exists
    const float mwB = (tx < 31) ? 1.f : 0.f;   // right halo exists

    const size_t plane = (size_t)GCA_H * GCA_W;
    const float* base = x   + ((size_t)b * GCA_C + c0) * plane;
    float* obase      = out + ((size_t)b * GCA_C + c0) * plane;

    const int r0off = hm * GCA_W + w0;
    const int r1off = h  * GCA_W + w0;
    const int r2off = hp * GCA_W + w0;

    float4 s[CPW];                       // scores, then exp values
    float4 lmax = make_float4(-3.0e38f, -3.0e38f, -3.0e38f, -3.0e38f);

    // Pass 1: conv + curvature scores for 4 pixels x 16 channels.
    #pragma unroll
    for (int i = 0; i < CPW; ++i) {
        const float* p = base + (size_t)i * plane;
        float4 v0 = *(const float4*)(p + r0off);
        const float4 v1 = *(const float4*)(p + r1off);
        float4 v2 = *(const float4*)(p + r2off);

        // Row-edge masks (identity except h=0 / h=127; unconditional to keep
        // the unrolled body straight-line -> VGPR stays at 64).
        v0.x *= mh0; v0.y *= mh0; v0.z *= mh0; v0.w *= mh0;
        v2.x *= mh2; v2.y *= mh2; v2.z *= mh2; v2.w *= mh2;

        // Own column sums for cols w0..w0+3 (A..D).
        const float cpA = fmaf(2.f, v1.x, v0.x + v2.x);
        const float cmA = v0.x - v2.x;
        const float cyA = fmaf(-4.f, v1.x, cpA);
        const float cpB = fmaf(2.f, v1.y, v0.y + v2.y);
        const float cmB = v0.y - v2.y;
        const float cyB = fmaf(-4.f, v1.y, cpB);
        const float cpC = fmaf(2.f, v1.z, v0.z + v2.z);
        const float cmC = v0.z - v2.z;
        const float cyC = fmaf(-4.f, v1.z, cpC);
        const float cpD = fmaf(2.f, v1.w, v0.w + v2.w);
        const float cmD = v0.w - v2.w;
        const float cyD = fmaf(-4.f, v1.w, cpD);

        // Halo column sums from neighbor lanes (row masks already applied).
        const float cpL = __shfl_up(cpD, 1) * mwA;
        const float cmL = __shfl_up(cmD, 1) * mwA;
        const float cyL = __shfl_up(cyD, 1) * mwA;
        const float cpR = __shfl_down(cpA, 1) * mwB;
        const float cmR = __shfl_down(cmA, 1) * mwB;
        const float cyR = __shfl_down(cyA, 1) * mwB;

        float4 sc;
        sc.x = gca_score12(cpL, cpA, cpB,  cmL, cmA, cmB,  cyL, cyA, cyB);
        sc.y = gca_score12(cpA, cpB, cpC,  cmA, cmB, cmC,  cyA, cyB, cyC);
        sc.z = gca_score12(cpB, cpC, cpD,  cmB, cmC, cmD,  cyB, cyC, cyD);
        sc.w = gca_score12(cpC, cpD, cpR,  cmC, cmD, cmR,  cyC, cyD, cyR);
        s[i] = sc;
        lmax.x = fmaxf(lmax.x, sc.x);
        lmax.y = fmaxf(lmax.y, sc.y);
        lmax.z = fmaxf(lmax.z, sc.z);
        lmax.w = fmaxf(lmax.w, sc.w);
    }

    // Cross-group softmax reduction (per pixel, over the 8 channel groups).
    __shared__ float4 redmax[CGRP][32];
    __shared__ float4 redsum[CGRP][32];

    redmax[ty][tx] = lmax;
    __syncthreads();
    float4 gmax = make_float4(-3.0e38f, -3.0e38f, -3.0e38f, -3.0e38f);
    #pragma unroll
    for (int g = 0; g < CGRP; ++g) {
        const float4 m = redmax[g][tx];
        gmax.x = fmaxf(gmax.x, m.x);
        gmax.y = fmaxf(gmax.y, m.y);
        gmax.z = fmaxf(gmax.z, m.z);
        gmax.w = fmaxf(gmax.w, m.w);
    }

    float4 lsum = make_float4(0.f, 0.f, 0.f, 0.f);
    #pragma unroll
    for (int i = 0; i < CPW; ++i) {
        float4 e;
        e.x = __builtin_amdgcn_exp2f((s[i].x - gmax.x) * GCA_LOG2E);
        e.y = __builtin_amdgcn_exp2f((s[i].y - gmax.y) * GCA_LOG2E);
        e.z = __builtin_amdgcn_exp2f((s[i].z - gmax.z) * GCA_LOG2E);
        e.w = __builtin_amdgcn_exp2f((s[i].w - gmax.w) * GCA_LOG2E);
        s[i] = e;
        lsum.x += e.x; lsum.y += e.y; lsum.z += e.z; lsum.w += e.w;
    }
    redsum[ty][tx] = lsum;
    __syncthreads();
    float4 tot = make_float4(0.f, 0.f, 0.f, 0.f);
    #pragma unroll
    for (int g = 0; g < CGRP; ++g) {
        const float4 sm = redsum[g][tx];
        tot.x += sm.x; tot.y += sm.y; tot.z += sm.z; tot.w += sm.w;
    }
    const float invx = __builtin_amdgcn_rcpf(tot.x);
    const float invy = __builtin_amdgcn_rcpf(tot.y);
    const float invz = __builtin_amdgcn_rcpf(tot.z);
    const float invw = __builtin_amdgcn_rcpf(tot.w);

    // Epilogue: out = (softmax + 1) * x; center row reloaded (L2-resident).
    #pragma unroll
    for (int i = 0; i < CPW; ++i) {
        const float4 xv = *(const float4*)(base + (size_t)i * plane + r1off);
        float4 o;
        o.x = fmaf(s[i].x * invx, xv.x, xv.x);
        o.y = fmaf(s[i].y * invy, xv.y, xv.y);
        o.z = fmaf(s[i].z * invz, xv.z, xv.z);
        o.w = fmaf(s[i].w * invw, xv.w, xv.w);
        *(float4*)(obase + (size_t)i * plane + r1off) = o;
    }
}

extern "C" void kernel_launch(void* const* d_in, const int* in_sizes, int n_in,
                              void* d_out, int out_size, void* d_ws, size_t ws_size,
                              hipStream_t stream) {
    (void)in_sizes; (void)n_in; (void)d_ws; (void)ws_size; (void)out_size;
    const float* x = (const float*)d_in[0];
    float* out = (float*)d_out;
    dim3 block(32, CGRP, 1);
    dim3 grid(GCA_B * GCA_H, 1, 1);   // 2048 blocks, swizzled in-kernel
    gca_fused12<<<grid, block, 0, stream>>>(x, out);
}

// Round 14
// 61.145 us; speedup vs baseline: 1.7244x; 1.0448x over previous
//
#include <hip/hip_runtime.h>

// GradientCurvatureAttention: fused depthwise-conv + curvature + channel-softmax + scale.
// x: [B=16, C=128, H=128, W=128] fp32, NCHW. out: same shape.
//
// Round 14: R12 base (63.9us, VGPR=64, traffic at compulsory floor) + NON-
// TEMPORAL output stores (fixed: builtin needs a NATIVE vector type, not
// HIP_vector_type). out is write-once/never-read -> stream it past L2/L3,
// freeing cache/fabric BW for the x read stream (pass-1 re-reads ~8.4 TB/s
// through L3). Straight-line substitution only; no branches, no launch-bound
// forcing (those blow VGPR: R9/R11).

#define GCA_B 16
#define GCA_C 128
#define GCA_H 128
#define GCA_W 128
#define CGRP  8            // channel groups (blockDim.y)
#define CPW   (GCA_C/CGRP) // 16 channels per group

#define GCA_LOG2E 1.44269504088896f

typedef float gca_f4 __attribute__((ext_vector_type(4)));  // native vec for NT store

__device__ __forceinline__ float gca_score14(float cpl, float cpc, float cpr,
                                             float cml, float cmc, float cmr,
                                             float cyl, float cyc, float cyr) {
    const float Gx  = cpl - cpr;                       // [1,2,1]v x [1,0,-1]h
    const float Gy  = fmaf(2.f, cmc, cml + cmr);       // [1,0,-1]v x [1,2,1]h
    const float Ixx = fmaf(-2.f, cpc, cpl + cpr);      // [1,2,1]v x [1,-2,1]h
    const float Ixy = cmr - cml;                       // [1,0,-1]v x [-1,0,1]h
    const float Iyy = fmaf(2.f, cyc, cyl + cyr);       // [1,-2,1]v x [1,2,1]h
    const float gy2 = Gy * Gy;
    const float g2e = fmaf(Gx, Gx, gy2 + 1e-6f);
    const float r   = __builtin_amdgcn_rsqf(g2e);      // raw v_rsq_f32
    const float gm  = g2e * r;                         // sqrt(g2e)
    const float t   = Gx * Iyy;
    const float p   = Gy * Ixy;
    const float inner = fmaf(-2.f, p, t);              // Gx*Iyy - 2*Gy*Ixy
    const float q   = gy2 * Ixx;
    const float num = fmaf(Gx, inner, q);
    const float r3  = (r * r) * r;
    return fmaf(num, r3, gm);                          // grad_mag + curvature
}

__global__ __launch_bounds__(256) void gca_fused14(const float* __restrict__ x,
                                                   float* __restrict__ out) {
    const int tx = threadIdx.x;                 // 0..31 : pixel quad, w0 = 4*tx
    const int ty = threadIdx.y;                 // 0..7  : channel group

    // XCD swizzle: 2048 blocks (= B*H, h minor), 256 consecutive ids per XCD.
    const int id  = blockIdx.x;
    const int swz = ((id & 7) << 8) | (id >> 3);
    const int h   = swz & 127;
    const int b   = swz >> 7;

    const int w0 = tx * 4;
    const int c0 = ty * CPW;

    const int hm = (h > 0) ? h - 1 : 0;
    const int hp = (h < GCA_H - 1) ? h + 1 : GCA_H - 1;
    const float mh0 = (h > 0) ? 1.f : 0.f;
    const float mh2 = (h < GCA_H - 1) ? 1.f : 0.f;
    const float mwA = (tx > 0) ? 1.f : 0.f;    // left halo exists
    const float mwB = (tx < 31) ? 1.f : 0.f;   // right halo exists

    const size_t plane = (size_t)GCA_H * GCA_W;
    const float* base = x   + ((size_t)b * GCA_C + c0) * plane;
    float* obase      = out + ((size_t)b * GCA_C + c0) * plane;

    const int r0off = hm * GCA_W + w0;
    const int r1off = h  * GCA_W + w0;
    const int r2off = hp * GCA_W + w0;

    float4 s[CPW];                       // scores, then exp values
    float4 lmax = make_float4(-3.0e38f, -3.0e38f, -3.0e38f, -3.0e38f);

    // Pass 1: conv + curvature scores for 4 pixels x 16 channels.
    #pragma unroll
    for (int i = 0; i < CPW; ++i) {
        const float* p = base + (size_t)i * plane;
        float4 v0 = *(const float4*)(p + r0off);
        const float4 v1 = *(const float4*)(p + r1off);
        float4 v2 = *(const float4*)(p + r2off);

        // Row-edge masks (identity except h=0 / h=127; unconditional to keep
        // the unrolled body straight-line -> VGPR stays at 64).
        v0.x *= mh0; v0.y *= mh0; v0.z *= mh0; v0.w *= mh0;
        v2.x *= mh2; v2.y *= mh2; v2.z *= mh2; v2.w *= mh2;

        // Own column sums for cols w0..w0+3 (A..D).
        const float cpA = fmaf(2.f, v1.x, v0.x + v2.x);
        const float cmA = v0.x - v2.x;
        const float cyA = fmaf(-4.f, v1.x, cpA);
        const float cpB = fmaf(2.f, v1.y, v0.y + v2.y);
        const float cmB = v0.y - v2.y;
        const float cyB = fmaf(-4.f, v1.y, cpB);
        const float cpC = fmaf(2.f, v1.z, v0.z + v2.z);
        const float cmC = v0.z - v2.z;
        const float cyC = fmaf(-4.f, v1.z, cpC);
        const float cpD = fmaf(2.f, v1.w, v0.w + v2.w);
        const float cmD = v0.w - v2.w;
        const float cyD = fmaf(-4.f, v1.w, cpD);

        // Halo column sums from neighbor lanes (row masks already applied).
        const float cpL = __shfl_up(cpD, 1) * mwA;
        const float cmL = __shfl_up(cmD, 1) * mwA;
        const float cyL = __shfl_up(cyD, 1) * mwA;
        const float cpR = __shfl_down(cpA, 1) * mwB;
        const float cmR = __shfl_down(cmA, 1) * mwB;
        const float cyR = __shfl_down(cyA, 1) * mwB;

        float4 sc;
        sc.x = gca_score14(cpL, cpA, cpB,  cmL, cmA, cmB,  cyL, cyA, cyB);
        sc.y = gca_score14(cpA, cpB, cpC,  cmA, cmB, cmC,  cyA, cyB, cyC);
        sc.z = gca_score14(cpB, cpC, cpD,  cmB, cmC, cmD,  cyB, cyC, cyD);
        sc.w = gca_score14(cpC, cpD, cpR,  cmC, cmD, cmR,  cyC, cyD, cyR);
        s[i] = sc;
        lmax.x = fmaxf(lmax.x, sc.x);
        lmax.y = fmaxf(lmax.y, sc.y);
        lmax.z = fmaxf(lmax.z, sc.z);
        lmax.w = fmaxf(lmax.w, sc.w);
    }

    // Cross-group softmax reduction (per pixel, over the 8 channel groups).
    __shared__ float4 redmax[CGRP][32];
    __shared__ float4 redsum[CGRP][32];

    redmax[ty][tx] = lmax;
    __syncthreads();
    float4 gmax = make_float4(-3.0e38f, -3.0e38f, -3.0e38f, -3.0e38f);
    #pragma unroll
    for (int g = 0; g < CGRP; ++g) {
        const float4 m = redmax[g][tx];
        gmax.x = fmaxf(gmax.x, m.x);
        gmax.y = fmaxf(gmax.y, m.y);
        gmax.z = fmaxf(gmax.z, m.z);
        gmax.w = fmaxf(gmax.w, m.w);
    }

    float4 lsum = make_float4(0.f, 0.f, 0.f, 0.f);
    #pragma unroll
    for (int i = 0; i < CPW; ++i) {
        float4 e;
        e.x = __builtin_amdgcn_exp2f((s[i].x - gmax.x) * GCA_LOG2E);
        e.y = __builtin_amdgcn_exp2f((s[i].y - gmax.y) * GCA_LOG2E);
        e.z = __builtin_amdgcn_exp2f((s[i].z - gmax.z) * GCA_LOG2E);
        e.w = __builtin_amdgcn_exp2f((s[i].w - gmax.w) * GCA_LOG2E);
        s[i] = e;
        lsum.x += e.x; lsum.y += e.y; lsum.z += e.z; lsum.w += e.w;
    }
    redsum[ty][tx] = lsum;
    __syncthreads();
    float4 tot = make_float4(0.f, 0.f, 0.f, 0.f);
    #pragma unroll
    for (int g = 0; g < CGRP; ++g) {
        const float4 sm = redsum[g][tx];
        tot.x += sm.x; tot.y += sm.y; tot.z += sm.z; tot.w += sm.w;
    }
    const float invx = __builtin_amdgcn_rcpf(tot.x);
    const float invy = __builtin_amdgcn_rcpf(tot.y);
    const float invz = __builtin_amdgcn_rcpf(tot.z);
    const float invw = __builtin_amdgcn_rcpf(tot.w);

    // Epilogue: out = (softmax + 1) * x; center row reloaded (L3-resident).
    // Output stores are NON-TEMPORAL: write-once data streams past L2/L3.
    #pragma unroll
    for (int i = 0; i < CPW; ++i) {
        const float4 xv = *(const float4*)(base + (size_t)i * plane + r1off);
        gca_f4 o;
        o.x = fmaf(s[i].x * invx, xv.x, xv.x);
        o.y = fmaf(s[i].y * invy, xv.y, xv.y);
        o.z = fmaf(s[i].z * invz, xv.z, xv.z);
        o.w = fmaf(s[i].w * invw, xv.w, xv.w);
        __builtin_nontemporal_store(o, (gca_f4*)(obase + (size_t)i * plane + r1off));
    }
}

extern "C" void kernel_launch(void* const* d_in, const int* in_sizes, int n_in,
                              void* d_out, int out_size, void* d_ws, size_t ws_size,
                              hipStream_t stream) {
    (void)in_sizes; (void)n_in; (void)d_ws; (void)ws_size; (void)out_size;
    const float* x = (const float*)d_in[0];
    float* out = (float*)d_out;
    dim3 block(32, CGRP, 1);
    dim3 grid(GCA_B * GCA_H, 1, 1);   // 2048 blocks, swizzled in-kernel
    gca_fused14<<<grid, block, 0, stream>>>(x, out);
}

// Round 15
// 57.772 us; speedup vs baseline: 1.8251x; 1.0584x over previous
//
#include <hip/hip_runtime.h>

// GradientCurvatureAttention: fused depthwise-conv + curvature + channel-softmax + scale.
// x: [B=16, C=128, H=128, W=128] fp32, NCHW. out: same shape.
//
// Round 15: R14 base (61.1us: R7 structure + intrinsics + NT stores) + center
// row CACHED IN REGISTERS from pass 1 (xc[i] = v1): kills the epilogue's 134MB
// L2/L3 reload stream and its dependent load->fma->store chain. Zero extra
// loads, straight-line (s[] already lives in the unified AGPR file; xc adds
// 64 more). Tripwire: WRITE_SIZE rise = spill -> revert.

#define GCA_B 16
#define GCA_C 128
#define GCA_H 128
#define GCA_W 128
#define CGRP  8            // channel groups (blockDim.y)
#define CPW   (GCA_C/CGRP) // 16 channels per group

#define GCA_LOG2E 1.44269504088896f

typedef float gca_f4 __attribute__((ext_vector_type(4)));  // native vec for NT store

__device__ __forceinline__ float gca_score15(float cpl, float cpc, float cpr,
                                             float cml, float cmc, float cmr,
                                             float cyl, float cyc, float cyr) {
    const float Gx  = cpl - cpr;                       // [1,2,1]v x [1,0,-1]h
    const float Gy  = fmaf(2.f, cmc, cml + cmr);       // [1,0,-1]v x [1,2,1]h
    const float Ixx = fmaf(-2.f, cpc, cpl + cpr);      // [1,2,1]v x [1,-2,1]h
    const float Ixy = cmr - cml;                       // [1,0,-1]v x [-1,0,1]h
    const float Iyy = fmaf(2.f, cyc, cyl + cyr);       // [1,-2,1]v x [1,2,1]h
    const float gy2 = Gy * Gy;
    const float g2e = fmaf(Gx, Gx, gy2 + 1e-6f);
    const float r   = __builtin_amdgcn_rsqf(g2e);      // raw v_rsq_f32
    const float gm  = g2e * r;                         // sqrt(g2e)
    const float t   = Gx * Iyy;
    const float p   = Gy * Ixy;
    const float inner = fmaf(-2.f, p, t);              // Gx*Iyy - 2*Gy*Ixy
    const float q   = gy2 * Ixx;
    const float num = fmaf(Gx, inner, q);
    const float r3  = (r * r) * r;
    return fmaf(num, r3, gm);                          // grad_mag + curvature
}

__global__ __launch_bounds__(256) void gca_fused15(const float* __restrict__ x,
                                                   float* __restrict__ out) {
    const int tx = threadIdx.x;                 // 0..31 : pixel quad, w0 = 4*tx
    const int ty = threadIdx.y;                 // 0..7  : channel group

    // XCD swizzle: 2048 blocks (= B*H, h minor), 256 consecutive ids per XCD.
    const int id  = blockIdx.x;
    const int swz = ((id & 7) << 8) | (id >> 3);
    const int h   = swz & 127;
    const int b   = swz >> 7;

    const int w0 = tx * 4;
    const int c0 = ty * CPW;

    const int hm = (h > 0) ? h - 1 : 0;
    const int hp = (h < GCA_H - 1) ? h + 1 : GCA_H - 1;
    const float mh0 = (h > 0) ? 1.f : 0.f;
    const float mh2 = (h < GCA_H - 1) ? 1.f : 0.f;
    const float mwA = (tx > 0) ? 1.f : 0.f;    // left halo exists
    const float mwB = (tx < 31) ? 1.f : 0.f;   // right halo exists

    const size_t plane = (size_t)GCA_H * GCA_W;
    const float* base = x   + ((size_t)b * GCA_C + c0) * plane;
    float* obase      = out + ((size_t)b * GCA_C + c0) * plane;

    const int r0off = hm * GCA_W + w0;
    const int r1off = h  * GCA_W + w0;
    const int r2off = hp * GCA_W + w0;

    float4 s[CPW];                       // scores, then exp values
    float4 xc[CPW];                      // center row, kept for the epilogue
    float4 lmax = make_float4(-3.0e38f, -3.0e38f, -3.0e38f, -3.0e38f);

    // Pass 1: conv + curvature scores for 4 pixels x 16 channels.
    #pragma unroll
    for (int i = 0; i < CPW; ++i) {
        const float* p = base + (size_t)i * plane;
        float4 v0 = *(const float4*)(p + r0off);
        const float4 v1 = *(const float4*)(p + r1off);
        float4 v2 = *(const float4*)(p + r2off);
        xc[i] = v1;

        // Row-edge masks (identity except h=0 / h=127; unconditional to keep
        // the unrolled body straight-line).
        v0.x *= mh0; v0.y *= mh0; v0.z *= mh0; v0.w *= mh0;
        v2.x *= mh2; v2.y *= mh2; v2.z *= mh2; v2.w *= mh2;

        // Own column sums for cols w0..w0+3 (A..D).
        const float cpA = fmaf(2.f, v1.x, v0.x + v2.x);
        const float cmA = v0.x - v2.x;
        const float cyA = fmaf(-4.f, v1.x, cpA);
        const float cpB = fmaf(2.f, v1.y, v0.y + v2.y);
        const float cmB = v0.y - v2.y;
        const float cyB = fmaf(-4.f, v1.y, cpB);
        const float cpC = fmaf(2.f, v1.z, v0.z + v2.z);
        const float cmC = v0.z - v2.z;
        const float cyC = fmaf(-4.f, v1.z, cpC);
        const float cpD = fmaf(2.f, v1.w, v0.w + v2.w);
        const float cmD = v0.w - v2.w;
        const float cyD = fmaf(-4.f, v1.w, cpD);

        // Halo column sums from neighbor lanes (row masks already applied).
        const float cpL = __shfl_up(cpD, 1) * mwA;
        const float cmL = __shfl_up(cmD, 1) * mwA;
        const float cyL = __shfl_up(cyD, 1) * mwA;
        const float cpR = __shfl_down(cpA, 1) * mwB;
        const float cmR = __shfl_down(cmA, 1) * mwB;
        const float cyR = __shfl_down(cyA, 1) * mwB;

        float4 sc;
        sc.x = gca_score15(cpL, cpA, cpB,  cmL, cmA, cmB,  cyL, cyA, cyB);
        sc.y = gca_score15(cpA, cpB, cpC,  cmA, cmB, cmC,  cyA, cyB, cyC);
        sc.z = gca_score15(cpB, cpC, cpD,  cmB, cmC, cmD,  cyB, cyC, cyD);
        sc.w = gca_score15(cpC, cpD, cpR,  cmC, cmD, cmR,  cyC, cyD, cyR);
        s[i] = sc;
        lmax.x = fmaxf(lmax.x, sc.x);
        lmax.y = fmaxf(lmax.y, sc.y);
        lmax.z = fmaxf(lmax.z, sc.z);
        lmax.w = fmaxf(lmax.w, sc.w);
    }

    // Cross-group softmax reduction (per pixel, over the 8 channel groups).
    __shared__ float4 redmax[CGRP][32];
    __shared__ float4 redsum[CGRP][32];

    redmax[ty][tx] = lmax;
    __syncthreads();
    float4 gmax = make_float4(-3.0e38f, -3.0e38f, -3.0e38f, -3.0e38f);
    #pragma unroll
    for (int g = 0; g < CGRP; ++g) {
        const float4 m = redmax[g][tx];
        gmax.x = fmaxf(gmax.x, m.x);
        gmax.y = fmaxf(gmax.y, m.y);
        gmax.z = fmaxf(gmax.z, m.z);
        gmax.w = fmaxf(gmax.w, m.w);
    }

    float4 lsum = make_float4(0.f, 0.f, 0.f, 0.f);
    #pragma unroll
    for (int i = 0; i < CPW; ++i) {
        float4 e;
        e.x = __builtin_amdgcn_exp2f((s[i].x - gmax.x) * GCA_LOG2E);
        e.y = __builtin_amdgcn_exp2f((s[i].y - gmax.y) * GCA_LOG2E);
        e.z = __builtin_amdgcn_exp2f((s[i].z - gmax.z) * GCA_LOG2E);
        e.w = __builtin_amdgcn_exp2f((s[i].w - gmax.w) * GCA_LOG2E);
        s[i] = e;
        lsum.x += e.x; lsum.y += e.y; lsum.z += e.z; lsum.w += e.w;
    }
    redsum[ty][tx] = lsum;
    __syncthreads();
    float4 tot = make_float4(0.f, 0.f, 0.f, 0.f);
    #pragma unroll
    for (int g = 0; g < CGRP; ++g) {
        const float4 sm = redsum[g][tx];
        tot.x += sm.x; tot.y += sm.y; tot.z += sm.z; tot.w += sm.w;
    }
    const float invx = __builtin_amdgcn_rcpf(tot.x);
    const float invy = __builtin_amdgcn_rcpf(tot.y);
    const float invz = __builtin_amdgcn_rcpf(tot.z);
    const float invw = __builtin_amdgcn_rcpf(tot.w);

    // Epilogue: out = (softmax + 1) * x, x from registers; NT stores.
    #pragma unroll
    for (int i = 0; i < CPW; ++i) {
        const float4 xv = xc[i];
        gca_f4 o;
        o.x = fmaf(s[i].x * invx, xv.x, xv.x);
        o.y = fmaf(s[i].y * invy, xv.y, xv.y);
        o.z = fmaf(s[i].z * invz, xv.z, xv.z);
        o.w = fmaf(s[i].w * invw, xv.w, xv.w);
        __builtin_nontemporal_store(o, (gca_f4*)(obase + (size_t)i * plane + r1off));
    }
}

extern "C" void kernel_launch(void* const* d_in, const int* in_sizes, int n_in,
                              void* d_out, int out_size, void* d_ws, size_t ws_size,
                              hipStream_t stream) {
    (void)in_sizes; (void)n_in; (void)d_ws; (void)ws_size; (void)out_size;
    const float* x = (const float*)d_in[0];
    float* out = (float*)d_out;
    dim3 block(32, CGRP, 1);
    dim3 grid(GCA_B * GCA_H, 1, 1);   // 2048 blocks, swizzled in-kernel
    gca_fused15<<<grid, block, 0, stream>>>(x, out);
}